// Round 1
// baseline (336.752 us; speedup 1.0000x reference)
//
#include <hip/hip_runtime.h>

// ---------------------------------------------------------------------------
// Fused MHA: B=2, T=2048, M=2048, H=16, D=128, causal, qk-centered-RMS-norm,
// half-split rotary, QK_SCALE = 1/D.
// Pipeline: cast/transposes -> QKV GEMM (bf16 MFMA) -> norm+rope -> flash attn
//           -> out GEMM (fp32 out).
// ---------------------------------------------------------------------------

#define NB 2
#define NT 2048
#define NM 2048
#define NH 16
#define ND 128

typedef __attribute__((ext_vector_type(4))) float f32x4;
typedef __attribute__((ext_vector_type(8))) short bf16x8;
typedef __attribute__((ext_vector_type(4))) short bf16x4;

#define AS1 __attribute__((address_space(1)))
#define AS3 __attribute__((address_space(3)))

__device__ __forceinline__ unsigned short f2bf(float f){
  unsigned int u = __float_as_uint(f);
  u = (u + 0x7fffu + ((u >> 16) & 1u)) >> 16;   // RNE
  return (unsigned short)u;
}
__device__ __forceinline__ float bf2f(short s){
  return __uint_as_float(((unsigned int)(unsigned short)s) << 16);
}
__device__ __forceinline__ float wredsum(float v){
  #pragma unroll
  for (int m = 1; m < 64; m <<= 1) v += __shfl_xor(v, m);
  return v;
}
__device__ __forceinline__ void gload_lds16(const void* g, void* l){
  __builtin_amdgcn_global_load_lds((const AS1 void*)g, (AS3 void*)l, 16, 0, 0);
}

// ---------------- rope cos/sin table: [T][64] each --------------------------
__global__ __launch_bounds__(64) void rope_table_k(float* ctab, float* stab){
  int t = blockIdx.x, i = threadIdx.x;
  float freq = __expf(-(float)i * (9.210340371976184f / 64.0f)); // ln(10000)
  float ang = (float)t * freq;
  ctab[t * 64 + i] = cosf(ang);
  stab[t * 64 + i] = sinf(ang);
}

// ---------------- cast x fp32 -> bf16 --------------------------------------
__global__ __launch_bounds__(256) void cast_x_k(const float* __restrict__ x,
                                                short* __restrict__ xb){
  size_t gid = (size_t)blockIdx.x * 256 + threadIdx.x;
  float4 v = *(const float4*)(x + gid * 4);
  bf16x4 o;
  o[0] = (short)f2bf(v.x); o[1] = (short)f2bf(v.y);
  o[2] = (short)f2bf(v.z); o[3] = (short)f2bf(v.w);
  *(bf16x4*)(xb + gid * 4) = o;
}

// ------------- transpose weights fp32 [K][N] -> bf16 [N][K] ----------------
// z selects wq,wk,wv,wo; dst = wT + z*2048*2048
__global__ __launch_bounds__(256) void transpose_w_k(const float* __restrict__ wq,
                                                     const float* __restrict__ wk,
                                                     const float* __restrict__ wv,
                                                     const float* __restrict__ wo,
                                                     short* __restrict__ wT){
  __shared__ float tl[32][33];
  int z = blockIdx.z;
  const float* src = (z == 0) ? wq : (z == 1) ? wk : (z == 2) ? wv : wo;
  short* dst = wT + (size_t)z * 2048 * 2048;
  int n0 = blockIdx.x * 32, k0 = blockIdx.y * 32;
  int cx = threadIdx.x & 31, ry = threadIdx.x >> 5; // 0..7
  #pragma unroll
  for (int p = 0; p < 4; ++p)
    tl[ry + 8 * p][cx] = src[(size_t)(k0 + ry + 8 * p) * 2048 + n0 + cx];
  __syncthreads();
  #pragma unroll
  for (int p = 0; p < 4; ++p)
    dst[(size_t)(n0 + ry + 8 * p) * 2048 + k0 + cx] =
        (short)f2bf(tl[cx][ry + 8 * p]);
}

// ---------------- GEMM: C[4096 x N] = A[4096 x K] * B^T[N x K] (bf16) ------
// MODE 0: N tiles over 6144 (q|k|v), scatter bf16 into [B,H,T,D] (3 tensors)
// MODE 1: N = 2048, fp32 row-major out
template<int MODE>
__global__ __launch_bounds__(256) void gemm_bt_k(const short* __restrict__ A,
                                                 const short* __restrict__ Bt,
                                                 void* __restrict__ Cout,
                                                 int Kdim){
  __shared__ short As[128 * 32];
  __shared__ short Bs[128 * 32];
  const int tid = threadIdx.x;
  const int wid = tid >> 6, lane = tid & 63;
  const int lrow = lane & 15, g8 = lane >> 4;
  const int wm = wid >> 1, wn = wid & 1;
  const int m0 = blockIdx.x * 128, n0 = blockIdx.y * 128;
  f32x4 acc[4][4] = {};
  const int srow = lane >> 2;        // staging: 16 rows per inst
  const int skcol = (lane & 3) * 8;  // 8 bf16 = 16B

  for (int kt = 0; kt < Kdim; kt += 32){
    __syncthreads();
    #pragma unroll
    for (int i = 0; i < 2; ++i){
      int inst = wid * 2 + i;
      int r = inst * 16 + srow;
      const short* sa = A  + (size_t)(m0 + r) * Kdim + kt + skcol;
      const short* sb = Bt + (size_t)(n0 + r) * Kdim + kt + skcol;
      gload_lds16(sa, (char*)As + inst * 1024);
      gload_lds16(sb, (char*)Bs + inst * 1024);
    }
    __syncthreads();
    bf16x8 af[4], bfv[4];
    #pragma unroll
    for (int mi = 0; mi < 4; ++mi)
      af[mi] = *(const bf16x8*)&As[(wm * 64 + mi * 16 + lrow) * 32 + g8 * 8];
    #pragma unroll
    for (int ni = 0; ni < 4; ++ni)
      bfv[ni] = *(const bf16x8*)&Bs[(wn * 64 + ni * 16 + lrow) * 32 + g8 * 8];
    #pragma unroll
    for (int mi = 0; mi < 4; ++mi)
      #pragma unroll
      for (int ni = 0; ni < 4; ++ni)
        acc[mi][ni] = __builtin_amdgcn_mfma_f32_16x16x32_bf16(
            af[mi], bfv[ni], acc[mi][ni], 0, 0, 0);
  }

  #pragma unroll
  for (int mi = 0; mi < 4; ++mi){
    int rowb = m0 + wm * 64 + mi * 16 + g8 * 4;     // + r  (bt index)
    #pragma unroll
    for (int ni = 0; ni < 4; ++ni){
      int col = n0 + wn * 64 + ni * 16 + lrow;
      f32x4 a = acc[mi][ni];
      if constexpr (MODE == 0){
        int tsel = col >> 11;          // 0,1,2 -> q,k,v
        int hd = col & 2047;
        int h = hd >> 7, d = hd & 127;
        short* dst = (short*)Cout + (size_t)tsel * (NB * NH * NT * ND);
        #pragma unroll
        for (int r = 0; r < 4; ++r){
          int bt = rowb + r;
          int b = bt >> 11, t = bt & 2047;
          dst[(((size_t)(b * NH + h)) * NT + t) * ND + d] = (short)f2bf(a[r]);
        }
      } else {
        float* dst = (float*)Cout;
        #pragma unroll
        for (int r = 0; r < 4; ++r)
          dst[(size_t)(rowb + r) * 2048 + col] = a[r];
      }
    }
  }
}

// -------------- centered RMS norm + rotary (q and k) -----------------------
// one wave per row; lane i owns the rotary pair (d=i, d=i+64)
__global__ __launch_bounds__(256) void norm_rope_k(const short* __restrict__ qkv,
                                                   short* __restrict__ outp,
                                                   const float* __restrict__ gq,
                                                   const float* __restrict__ bq,
                                                   const float* __restrict__ gk,
                                                   const float* __restrict__ bk,
                                                   const float* __restrict__ ctab,
                                                   const float* __restrict__ stab){
  int which = blockIdx.y;
  const short* src = qkv + (size_t)which * (NB * NH * NT * ND);
  short* dst = outp + (size_t)which * (NB * NH * NT * ND);
  const float* g = which ? gk : gq;
  const float* bb = which ? bk : bq;
  int wid = threadIdx.x >> 6, lane = threadIdx.x & 63;
  size_t row = (size_t)blockIdx.x * 4 + wid;  // over B*H*T
  int h = (int)((row >> 11) & 15);
  int t = (int)(row & 2047);
  const short* rp = src + row * ND;
  float v0 = bf2f(rp[lane]), v1 = bf2f(rp[lane + 64]);
  float mean = wredsum(v0 + v1) * (1.0f / 128.0f);
  float c0 = v0 - mean, c1 = v1 - mean;
  float ms = wredsum(c0 * c0 + c1 * c1) * (1.0f / 128.0f);
  float rstd = rsqrtf(ms + 1e-6f);
  float n0 = c0 * rstd * (1.0f + g[h * ND + lane]) + bb[h * ND + lane];
  float n1 = c1 * rstd * (1.0f + g[h * ND + lane + 64]) + bb[h * ND + lane + 64];
  float co = ctab[t * 64 + lane], si = stab[t * 64 + lane];
  short* wp = dst + row * ND;
  wp[lane]      = (short)f2bf(n0 * co - n1 * si);
  wp[lane + 64] = (short)f2bf(n0 * si + n1 * co);
}

// ---------------- flash attention, causal ----------------------------------
// block: 4 waves x 16 q-rows = 64-row Q tile; KV tile 64 staged in LDS.
// Swapped QK^T: S^T = mfma(A=K, B=Q^T); O^T = mfma(A=V^T, B=P^T).
__global__ __launch_bounds__(256) void attn_k(const short* __restrict__ qn,
                                              const short* __restrict__ kn,
                                              const short* __restrict__ vsrc,
                                              short* __restrict__ ob){
  __shared__ short Ks[64 * 128];    // [j][d], XOR-swizzled rows (256B)
  __shared__ short VTs[128 * 64];   // [d][j], XOR-swizzled rows (128B)
  __shared__ short Ps[4][16 * 64];  // per-wave [q][j], XOR-swizzled
  const int tid = threadIdx.x;
  const int wid = tid >> 6, lane = tid & 63;
  const int lrow = lane & 15, g8 = lane >> 4;
  const int bh = blockIdx.y;
  const int b = bh >> 4, h = bh & 15;
  const size_t base = (size_t)bh * NT * ND;

  for (int pass = 0; pass < 2; ++pass){
    const int qt = pass ? (31 - (int)blockIdx.x) : (int)blockIdx.x;
    const int t0 = qt * 64;
    const int tq = t0 + wid * 16 + lrow;   // this lane's query row (= S^T col)
    bf16x8 qf[4];
    #pragma unroll
    for (int dc = 0; dc < 4; ++dc)
      qf[dc] = *(const bf16x8*)(qn + base + (size_t)tq * ND + dc * 32 + g8 * 8);
    f32x4 O[8] = {};
    float m = -3e38f, lsum = 0.0f;
    const int ntiles = qt + 1;

    for (int jb = 0; jb < ntiles; ++jb){
      __syncthreads();
      // ---- stage K [64][128] swizzled ----
      #pragma unroll
      for (int p = 0; p < 4; ++p){
        int r = (tid >> 4) + p * 16;
        int c = tid & 15;
        bf16x8 kv = *(const bf16x8*)(kn + base + (size_t)(jb * 64 + r) * ND + c * 8);
        *(bf16x8*)((char*)Ks + r * 256 + ((c * 16) ^ ((r & 7) << 4))) = kv;
      }
      // ---- stage V^T [128][64] swizzled ----
      #pragma unroll
      for (int p = 0; p < 4; ++p){
        int jr = (tid >> 4) + p * 16;
        int d0 = (tid & 15) * 8;
        bf16x8 vv = *(const bf16x8*)(vsrc + base + (size_t)(jb * 64 + jr) * ND + d0);
        #pragma unroll
        for (int i = 0; i < 8; ++i){
          int d = d0 + i;
          *(short*)((char*)VTs + d * 128 +
                    ((jr * 2) ^ ((((d >> 3) ^ d) & 7) << 4))) = vv[i];
        }
      }
      __syncthreads();

      if (jb * 64 <= t0 + wid * 16 + 15){   // wave has unmasked work
        // ---- S^T = K * Q^T over D=128 ----
        f32x4 st[4] = {};
        #pragma unroll
        for (int dc = 0; dc < 4; ++dc)
          #pragma unroll
          for (int js = 0; js < 4; ++js){
            int jl = js * 16 + lrow;
            bf16x8 kf = *(const bf16x8*)((char*)Ks + jl * 256 +
                          ((dc * 64 + g8 * 16) ^ ((jl & 7) << 4)));
            st[js] = __builtin_amdgcn_mfma_f32_16x16x32_bf16(kf, qf[dc], st[js], 0, 0, 0);
          }
        // ---- scale + causal mask + row max ----
        float mx = -3e38f;
        #pragma unroll
        for (int js = 0; js < 4; ++js)
          #pragma unroll
          for (int r = 0; r < 4; ++r){
            float s = st[js][r] * (1.0f / 128.0f);
            int j = jb * 64 + js * 16 + g8 * 4 + r;
            if (j > tq) s = -3e38f;
            st[js][r] = s;
            mx = fmaxf(mx, s);
          }
        mx = fmaxf(mx, __shfl_xor(mx, 16));
        mx = fmaxf(mx, __shfl_xor(mx, 32));
        float mnew = fmaxf(m, mx);
        float fac = __expf(m - mnew);
        m = mnew;
        lsum *= fac;
        #pragma unroll
        for (int dcb = 0; dcb < 8; ++dcb) O[dcb] *= fac;
        // ---- P = exp(S - m), write P[q][j] to swizzled LDS ----
        float ps = 0.0f;
        #pragma unroll
        for (int js = 0; js < 4; ++js)
          #pragma unroll
          for (int r = 0; r < 4; ++r){
            float p = __expf(st[js][r] - mnew);
            ps += p;
            int jl = js * 16 + g8 * 4 + r;
            *(short*)((char*)Ps[wid] + lrow * 128 +
                      ((jl * 2) ^ ((lrow & 7) << 4))) = (short)f2bf(p);
          }
        ps += __shfl_xor(ps, 16);
        ps += __shfl_xor(ps, 32);
        lsum += ps;
        asm volatile("s_waitcnt lgkmcnt(0)" ::: "memory");
        // ---- O^T += V^T * P^T ----
        #pragma unroll
        for (int j32 = 0; j32 < 2; ++j32){
          bf16x8 pf = *(const bf16x8*)((char*)Ps[wid] + lrow * 128 +
                        ((j32 * 64 + g8 * 16) ^ ((lrow & 7) << 4)));
          #pragma unroll
          for (int dcb = 0; dcb < 8; ++dcb){
            int d = dcb * 16 + lrow;
            bf16x8 vf = *(const bf16x8*)((char*)VTs + d * 128 +
                          ((j32 * 64 + g8 * 16) ^ ((((d >> 3) ^ d) & 7) << 4)));
            O[dcb] = __builtin_amdgcn_mfma_f32_16x16x32_bf16(vf, pf, O[dcb], 0, 0, 0);
          }
        }
      }
    }
    // ---- write O row tq as bf16 into [bt][h*128+d] ----
    float inv = 1.0f / lsum;
    #pragma unroll
    for (int dcb = 0; dcb < 8; ++dcb){
      bf16x4 w4;
      #pragma unroll
      for (int r = 0; r < 4; ++r) w4[r] = (short)f2bf(O[dcb][r] * inv);
      *(bf16x4*)(ob + ((size_t)(b * NT + tq)) * (NH * ND) + h * ND + dcb * 16 + g8 * 4) = w4;
    }
  }
}

// ---------------------------------------------------------------------------
extern "C" void kernel_launch(void* const* d_in, const int* in_sizes, int n_in,
                              void* d_out, int out_size, void* d_ws, size_t ws_size,
                              hipStream_t stream){
  const float* x  = (const float*)d_in[0];
  const float* wq = (const float*)d_in[1];
  const float* wk = (const float*)d_in[2];
  const float* wv = (const float*)d_in[3];
  const float* wo = (const float*)d_in[4];
  const float* gq = (const float*)d_in[5];
  const float* bq = (const float*)d_in[6];
  const float* gk = (const float*)d_in[7];
  const float* bk = (const float*)d_in[8];

  char* ws = (char*)d_ws;
  short* xb   = (short*)(ws);                      // 16,777,216 B
  short* wT   = (short*)(ws + 16777216);           // 33,554,432 B (q,k,v,o ^T)
  short* qkvb = (short*)(ws + 50331648);           // 50,331,648 B (q|k|v bf16 BHTD)
  short* qkn  = (short*)(ws + 100663296);          // 33,554,432 B (qn|kn)
  short* ob   = (short*)(ws + 134217728);          // 16,777,216 B
  float* ctab = (float*)(ws + 150994944);          // 524,288 B
  float* stab = (float*)(ws + 151519232);          // 524,288 B

  rope_table_k<<<dim3(2048), dim3(64), 0, stream>>>(ctab, stab);
  cast_x_k<<<dim3(8192), dim3(256), 0, stream>>>(x, xb);
  transpose_w_k<<<dim3(64, 64, 4), dim3(256), 0, stream>>>(wq, wk, wv, wo, wT);
  gemm_bt_k<0><<<dim3(32, 48), dim3(256), 0, stream>>>(xb, wT, qkvb, 2048);
  norm_rope_k<<<dim3(16384, 2), dim3(256), 0, stream>>>(qkvb, qkn, gq, bq, gk, bk, ctab, stab);
  attn_k<<<dim3(16, 32), dim3(256), 0, stream>>>(qkn, qkn + 8388608,
                                                 qkvb + 2 * (size_t)8388608, ob);
  gemm_bt_k<1><<<dim3(32, 16), dim3(256), 0, stream>>>(ob, wT + 3 * (size_t)4194304,
                                                       d_out, 2048);
}

// Round 3
// 323.348 us; speedup vs baseline: 1.0415x; 1.0415x over previous
//
#include <hip/hip_runtime.h>

// ---------------------------------------------------------------------------
// Fused MHA: B=2, T=2048, M=2048, H=16, D=128, causal, qk-centered-RMS-norm,
// half-split rotary, QK_SCALE = 1/D.
// Pipeline: cast/transposes -> QKV GEMM (256^2 8-wave bf16 MFMA) -> norm+rope
//           -> flash attn -> out GEMM (fp32 out).
// ---------------------------------------------------------------------------

#define NB 2
#define NT 2048
#define NM 2048
#define NH 16
#define ND 128

typedef __attribute__((ext_vector_type(4))) float f32x4;
typedef __attribute__((ext_vector_type(8))) short bf16x8;
typedef __attribute__((ext_vector_type(4))) short bf16x4;

#define AS1 __attribute__((address_space(1)))
#define AS3 __attribute__((address_space(3)))

__device__ __forceinline__ unsigned short f2bf(float f){
  unsigned int u = __float_as_uint(f);
  u = (u + 0x7fffu + ((u >> 16) & 1u)) >> 16;   // RNE
  return (unsigned short)u;
}
__device__ __forceinline__ float bf2f(short s){
  return __uint_as_float(((unsigned int)(unsigned short)s) << 16);
}
__device__ __forceinline__ float wredsum(float v){
  #pragma unroll
  for (int m = 1; m < 64; m <<= 1) v += __shfl_xor(v, m);
  return v;
}
__device__ __forceinline__ void gload_lds16(const void* g, void* l){
  __builtin_amdgcn_global_load_lds((const AS1 void*)g, (AS3 void*)l, 16, 0, 0);
}

// ---------------- rope cos/sin table: [T][64] each --------------------------
__global__ __launch_bounds__(64) void rope_table_k(float* ctab, float* stab){
  int t = blockIdx.x, i = threadIdx.x;
  float freq = __expf(-(float)i * (9.210340371976184f / 64.0f)); // ln(10000)
  float ang = (float)t * freq;
  ctab[t * 64 + i] = cosf(ang);
  stab[t * 64 + i] = sinf(ang);
}

// ---------------- cast x fp32 -> bf16 --------------------------------------
__global__ __launch_bounds__(256) void cast_x_k(const float* __restrict__ x,
                                                short* __restrict__ xb){
  size_t gid = (size_t)blockIdx.x * 256 + threadIdx.x;
  float4 v = *(const float4*)(x + gid * 4);
  bf16x4 o;
  o[0] = (short)f2bf(v.x); o[1] = (short)f2bf(v.y);
  o[2] = (short)f2bf(v.z); o[3] = (short)f2bf(v.w);
  *(bf16x4*)(xb + gid * 4) = o;
}

// ------------- transpose weights fp32 [K][N] -> bf16 [N][K] ----------------
__global__ __launch_bounds__(256) void transpose_w_k(const float* __restrict__ wq,
                                                     const float* __restrict__ wk,
                                                     const float* __restrict__ wv,
                                                     const float* __restrict__ wo,
                                                     short* __restrict__ wT){
  __shared__ float tl[32][33];
  int z = blockIdx.z;
  const float* src = (z == 0) ? wq : (z == 1) ? wk : (z == 2) ? wv : wo;
  short* dst = wT + (size_t)z * 2048 * 2048;
  int n0 = blockIdx.x * 32, k0 = blockIdx.y * 32;
  int cx = threadIdx.x & 31, ry = threadIdx.x >> 5; // 0..7
  #pragma unroll
  for (int p = 0; p < 4; ++p)
    tl[ry + 8 * p][cx] = src[(size_t)(k0 + ry + 8 * p) * 2048 + n0 + cx];
  __syncthreads();
  #pragma unroll
  for (int p = 0; p < 4; ++p)
    dst[(size_t)(n0 + ry + 8 * p) * 2048 + k0 + cx] =
        (short)f2bf(tl[cx][ry + 8 * p]);
}

// ---------------------------------------------------------------------------
// QKV GEMM: C[4096 x 6144] = A[4096 x 2048] * B^T[6144 x 2048] (bf16)
// 256x256 tile, BK=64, 8 waves (2M x 4N), 512 threads, 128 KiB dynamic LDS.
// T1 XCD swizzle, T2 LDS XOR swizzle, counted vmcnt prefetch, T5 setprio.
// Scatter epilogue: bf16 into q|k|v [B,H,T,D].
// ---------------------------------------------------------------------------
#define NKT 32   // 2048 / 64
__global__ __launch_bounds__(512, 2) void gemm256_k(const short* __restrict__ A,
                                                    const short* __restrict__ Bt,
                                                    short* __restrict__ Cq){
  extern __shared__ char lds[];   // [mat(2)][buf(2)][half(2)][128][64] bf16
  const int tid = threadIdx.x;
  const int wid = tid >> 6, lane = tid & 63;
  const int lrow = lane & 15, g8 = lane >> 4;
  const int wm = wid >> 2, wn = wid & 3;
  const int Kdim = 2048;

  // XCD-aware bijective swizzle over 384 blocks (384 % 8 == 0)
  int bid = blockIdx.x;
  int s = (bid & 7) * 48 + (bid >> 3);
  const int bx = s & 15;        // 16 m-tiles
  const int by = s >> 4;        // 24 n-tiles
  const int m0 = bx * 256, n0 = by * 256;

  // staging constants: thread covers (row = wid*8 + lane>>3, granule swizzled)
  const int r8 = lane >> 3;
  const int gcol = ((lane & 7) ^ r8) * 8;           // pre-swizzled k element
  const short* Ab = A  + (size_t)(m0 + wid * 8 + r8) * Kdim + gcol;
  const short* Bb = Bt + (size_t)(n0 + wid * 8 + r8) * Kdim + gcol;

  f32x4 acc[8][4] = {};

  auto STAGE = [&](int c, int kt){
    #pragma unroll
    for (int h = 0; h < 2; ++h)
      #pragma unroll
      for (int l = 0; l < 2; ++l){
        size_t roff = (size_t)(h * 128 + l * 64) * Kdim + kt * 64;
        char* la = lds + c * 32768 + h * 16384 + l * 8192 + wid * 1024;
        gload_lds16(Ab + roff, la);
        gload_lds16(Bb + roff, la + 65536);
      }
  };
  auto ldA = [&](int c, int mi, int kk) -> bf16x8 {
    int row = mi * 16 + lrow;
    int col = (kk * 64 + g8 * 16) ^ ((lrow & 7) << 4);
    return *(const bf16x8*)(lds + c * 32768 + wm * 16384 + row * 128 + col);
  };
  auto ldB = [&](int c, int ni, int kk) -> bf16x8 {
    int row = (wn & 1) * 64 + ni * 16 + lrow;
    int col = (kk * 64 + g8 * 16) ^ ((lrow & 7) << 4);
    return *(const bf16x8*)(lds + 65536 + c * 32768 + (wn >> 1) * 16384 + row * 128 + col);
  };

  STAGE(0, 0);   // prologue

  for (int kt = 0; kt < NKT; ++kt){
    const int c = kt & 1;
    if (kt + 1 < NKT){
      STAGE(c ^ 1, kt + 1);
      asm volatile("s_waitcnt vmcnt(8)" ::: "memory");   // drain 4-phase-old loads only
    } else {
      asm volatile("s_waitcnt vmcnt(0)" ::: "memory");
    }
    __builtin_amdgcn_s_barrier();

    bf16x8 bfr[4], afr[4];
    // ---- phase 0: mi 0-3, kk 0 ----
    #pragma unroll
    for (int ni = 0; ni < 4; ++ni) bfr[ni] = ldB(c, ni, 0);
    #pragma unroll
    for (int mi = 0; mi < 4; ++mi) afr[mi] = ldA(c, mi, 0);
    asm volatile("s_waitcnt lgkmcnt(0)" ::: "memory");
    __builtin_amdgcn_sched_barrier(0);
    __builtin_amdgcn_s_setprio(1);
    #pragma unroll
    for (int mi = 0; mi < 4; ++mi)
      #pragma unroll
      for (int ni = 0; ni < 4; ++ni)
        acc[mi][ni] = __builtin_amdgcn_mfma_f32_16x16x32_bf16(afr[mi], bfr[ni], acc[mi][ni], 0, 0, 0);
    __builtin_amdgcn_s_setprio(0);
    __builtin_amdgcn_s_barrier();
    // ---- phase 1: mi 4-7, kk 0 (bfr reused) ----
    #pragma unroll
    for (int mi = 0; mi < 4; ++mi) afr[mi] = ldA(c, mi + 4, 0);
    asm volatile("s_waitcnt lgkmcnt(0)" ::: "memory");
    __builtin_amdgcn_sched_barrier(0);
    __builtin_amdgcn_s_setprio(1);
    #pragma unroll
    for (int mi = 0; mi < 4; ++mi)
      #pragma unroll
      for (int ni = 0; ni < 4; ++ni)
        acc[mi + 4][ni] = __builtin_amdgcn_mfma_f32_16x16x32_bf16(afr[mi], bfr[ni], acc[mi + 4][ni], 0, 0, 0);
    __builtin_amdgcn_s_setprio(0);
    __builtin_amdgcn_s_barrier();
    // ---- phase 2: mi 0-3, kk 1 ----
    #pragma unroll
    for (int ni = 0; ni < 4; ++ni) bfr[ni] = ldB(c, ni, 1);
    #pragma unroll
    for (int mi = 0; mi < 4; ++mi) afr[mi] = ldA(c, mi, 1);
    asm volatile("s_waitcnt lgkmcnt(0)" ::: "memory");
    __builtin_amdgcn_sched_barrier(0);
    __builtin_amdgcn_s_setprio(1);
    #pragma unroll
    for (int mi = 0; mi < 4; ++mi)
      #pragma unroll
      for (int ni = 0; ni < 4; ++ni)
        acc[mi][ni] = __builtin_amdgcn_mfma_f32_16x16x32_bf16(afr[mi], bfr[ni], acc[mi][ni], 0, 0, 0);
    __builtin_amdgcn_s_setprio(0);
    __builtin_amdgcn_s_barrier();
    // ---- phase 3: mi 4-7, kk 1 ----
    #pragma unroll
    for (int mi = 0; mi < 4; ++mi) afr[mi] = ldA(c, mi + 4, 1);
    asm volatile("s_waitcnt lgkmcnt(0)" ::: "memory");
    __builtin_amdgcn_sched_barrier(0);
    __builtin_amdgcn_s_setprio(1);
    #pragma unroll
    for (int mi = 0; mi < 4; ++mi)
      #pragma unroll
      for (int ni = 0; ni < 4; ++ni)
        acc[mi + 4][ni] = __builtin_amdgcn_mfma_f32_16x16x32_bf16(afr[mi], bfr[ni], acc[mi + 4][ni], 0, 0, 0);
    __builtin_amdgcn_s_setprio(0);
    __builtin_amdgcn_s_barrier();   // end-of-tile: buffer c free for kt+2 staging
  }

  // ---- scatter epilogue: bf16 into q|k|v [B,H,T,D] ----
  #pragma unroll
  for (int mi = 0; mi < 8; ++mi){
    int rowb = m0 + wm * 128 + mi * 16 + g8 * 4;
    #pragma unroll
    for (int ni = 0; ni < 4; ++ni){
      int col = n0 + wn * 64 + ni * 16 + lrow;
      int tsel = col >> 11;
      int hd = col & 2047;
      int hh = hd >> 7, d = hd & 127;
      short* dst = Cq + (size_t)tsel * (NB * NH * NT * ND);
      f32x4 a = acc[mi][ni];
      #pragma unroll
      for (int r = 0; r < 4; ++r){
        int bt = rowb + r;
        int b = bt >> 11, t = bt & 2047;
        dst[(((size_t)(b * NH + hh)) * NT + t) * ND + d] = (short)f2bf(a[r]);
      }
    }
  }
}

// ---------------- GEMM (128^2 m97-structure): out projection ---------------
// C[4096 x 2048] = A[4096 x K] * B^T[2048 x K], fp32 row-major out
__global__ __launch_bounds__(256) void gemm_bt_k(const short* __restrict__ A,
                                                 const short* __restrict__ Bt,
                                                 float* __restrict__ Cout,
                                                 int Kdim){
  __shared__ short As[128 * 32];
  __shared__ short Bs[128 * 32];
  const int tid = threadIdx.x;
  const int wid = tid >> 6, lane = tid & 63;
  const int lrow = lane & 15, g8 = lane >> 4;
  const int wm = wid >> 1, wn = wid & 1;
  const int m0 = blockIdx.x * 128, n0 = blockIdx.y * 128;
  f32x4 acc[4][4] = {};
  const int srow = lane >> 2;
  const int skcol = (lane & 3) * 8;

  for (int kt = 0; kt < Kdim; kt += 32){
    __syncthreads();
    #pragma unroll
    for (int i = 0; i < 2; ++i){
      int inst = wid * 2 + i;
      int r = inst * 16 + srow;
      const short* sa = A  + (size_t)(m0 + r) * Kdim + kt + skcol;
      const short* sb = Bt + (size_t)(n0 + r) * Kdim + kt + skcol;
      gload_lds16(sa, (char*)As + inst * 1024);
      gload_lds16(sb, (char*)Bs + inst * 1024);
    }
    __syncthreads();
    bf16x8 af[4], bfv[4];
    #pragma unroll
    for (int mi = 0; mi < 4; ++mi)
      af[mi] = *(const bf16x8*)&As[(wm * 64 + mi * 16 + lrow) * 32 + g8 * 8];
    #pragma unroll
    for (int ni = 0; ni < 4; ++ni)
      bfv[ni] = *(const bf16x8*)&Bs[(wn * 64 + ni * 16 + lrow) * 32 + g8 * 8];
    #pragma unroll
    for (int mi = 0; mi < 4; ++mi)
      #pragma unroll
      for (int ni = 0; ni < 4; ++ni)
        acc[mi][ni] = __builtin_amdgcn_mfma_f32_16x16x32_bf16(
            af[mi], bfv[ni], acc[mi][ni], 0, 0, 0);
  }

  #pragma unroll
  for (int mi = 0; mi < 4; ++mi){
    int rowb = m0 + wm * 64 + mi * 16 + g8 * 4;
    #pragma unroll
    for (int ni = 0; ni < 4; ++ni){
      int col = n0 + wn * 64 + ni * 16 + lrow;
      f32x4 a = acc[mi][ni];
      #pragma unroll
      for (int r = 0; r < 4; ++r)
        Cout[(size_t)(rowb + r) * 2048 + col] = a[r];
    }
  }
}

// -------------- centered RMS norm + rotary (q and k) -----------------------
__global__ __launch_bounds__(256) void norm_rope_k(const short* __restrict__ qkv,
                                                   short* __restrict__ outp,
                                                   const float* __restrict__ gq,
                                                   const float* __restrict__ bq,
                                                   const float* __restrict__ gk,
                                                   const float* __restrict__ bk,
                                                   const float* __restrict__ ctab,
                                                   const float* __restrict__ stab){
  int which = blockIdx.y;
  const short* src = qkv + (size_t)which * (NB * NH * NT * ND);
  short* dst = outp + (size_t)which * (NB * NH * NT * ND);
  const float* g = which ? gk : gq;
  const float* bb = which ? bk : bq;
  int wid = threadIdx.x >> 6, lane = threadIdx.x & 63;
  size_t row = (size_t)blockIdx.x * 4 + wid;  // over B*H*T
  int h = (int)((row >> 11) & 15);
  int t = (int)(row & 2047);
  const short* rp = src + row * ND;
  float v0 = bf2f(rp[lane]), v1 = bf2f(rp[lane + 64]);
  float mean = wredsum(v0 + v1) * (1.0f / 128.0f);
  float c0 = v0 - mean, c1 = v1 - mean;
  float ms = wredsum(c0 * c0 + c1 * c1) * (1.0f / 128.0f);
  float rstd = rsqrtf(ms + 1e-6f);
  float n0 = c0 * rstd * (1.0f + g[h * ND + lane]) + bb[h * ND + lane];
  float n1 = c1 * rstd * (1.0f + g[h * ND + lane + 64]) + bb[h * ND + lane + 64];
  float co = ctab[t * 64 + lane], si = stab[t * 64 + lane];
  short* wp = dst + row * ND;
  wp[lane]      = (short)f2bf(n0 * co - n1 * si);
  wp[lane + 64] = (short)f2bf(n0 * si + n1 * co);
}

// ---------------- flash attention, causal ----------------------------------
__global__ __launch_bounds__(256) void attn_k(const short* __restrict__ qn,
                                              const short* __restrict__ kn,
                                              const short* __restrict__ vsrc,
                                              short* __restrict__ ob){
  __shared__ short Ks[64 * 128];
  __shared__ short VTs[128 * 64];
  __shared__ short Ps[4][16 * 64];
  const int tid = threadIdx.x;
  const int wid = tid >> 6, lane = tid & 63;
  const int lrow = lane & 15, g8 = lane >> 4;
  const int bh = blockIdx.y;
  const int b = bh >> 4, h = bh & 15;
  const size_t base = (size_t)bh * NT * ND;

  for (int pass = 0; pass < 2; ++pass){
    const int qt = pass ? (31 - (int)blockIdx.x) : (int)blockIdx.x;
    const int t0 = qt * 64;
    const int tq = t0 + wid * 16 + lrow;
    bf16x8 qf[4];
    #pragma unroll
    for (int dc = 0; dc < 4; ++dc)
      qf[dc] = *(const bf16x8*)(qn + base + (size_t)tq * ND + dc * 32 + g8 * 8);
    f32x4 O[8] = {};
    float m = -3e38f, lsum = 0.0f;
    const int ntiles = qt + 1;

    for (int jb = 0; jb < ntiles; ++jb){
      __syncthreads();
      #pragma unroll
      for (int p = 0; p < 4; ++p){
        int r = (tid >> 4) + p * 16;
        int c = tid & 15;
        bf16x8 kv = *(const bf16x8*)(kn + base + (size_t)(jb * 64 + r) * ND + c * 8);
        *(bf16x8*)((char*)Ks + r * 256 + ((c * 16) ^ ((r & 7) << 4))) = kv;
      }
      #pragma unroll
      for (int p = 0; p < 4; ++p){
        int jr = (tid >> 4) + p * 16;
        int d0 = (tid & 15) * 8;
        bf16x8 vv = *(const bf16x8*)(vsrc + base + (size_t)(jb * 64 + jr) * ND + d0);
        #pragma unroll
        for (int i = 0; i < 8; ++i){
          int d = d0 + i;
          *(short*)((char*)VTs + d * 128 +
                    ((jr * 2) ^ ((((d >> 3) ^ d) & 7) << 4))) = vv[i];
        }
      }
      __syncthreads();

      if (jb * 64 <= t0 + wid * 16 + 15){
        f32x4 st[4] = {};
        #pragma unroll
        for (int dc = 0; dc < 4; ++dc)
          #pragma unroll
          for (int js = 0; js < 4; ++js){
            int jl = js * 16 + lrow;
            bf16x8 kf = *(const bf16x8*)((char*)Ks + jl * 256 +
                          ((dc * 64 + g8 * 16) ^ ((jl & 7) << 4)));
            st[js] = __builtin_amdgcn_mfma_f32_16x16x32_bf16(kf, qf[dc], st[js], 0, 0, 0);
          }
        float mx = -3e38f;
        #pragma unroll
        for (int js = 0; js < 4; ++js)
          #pragma unroll
          for (int r = 0; r < 4; ++r){
            float s = st[js][r] * (1.0f / 128.0f);
            int j = jb * 64 + js * 16 + g8 * 4 + r;
            if (j > tq) s = -3e38f;
            st[js][r] = s;
            mx = fmaxf(mx, s);
          }
        mx = fmaxf(mx, __shfl_xor(mx, 16));
        mx = fmaxf(mx, __shfl_xor(mx, 32));
        float mnew = fmaxf(m, mx);
        float fac = __expf(m - mnew);
        m = mnew;
        lsum *= fac;
        #pragma unroll
        for (int dcb = 0; dcb < 8; ++dcb) O[dcb] *= fac;
        float ps = 0.0f;
        #pragma unroll
        for (int js = 0; js < 4; ++js)
          #pragma unroll
          for (int r = 0; r < 4; ++r){
            float p = __expf(st[js][r] - mnew);
            ps += p;
            int jl = js * 16 + g8 * 4 + r;
            *(short*)((char*)Ps[wid] + lrow * 128 +
                      ((jl * 2) ^ ((lrow & 7) << 4))) = (short)f2bf(p);
          }
        ps += __shfl_xor(ps, 16);
        ps += __shfl_xor(ps, 32);
        lsum += ps;
        asm volatile("s_waitcnt lgkmcnt(0)" ::: "memory");
        #pragma unroll
        for (int j32 = 0; j32 < 2; ++j32){
          bf16x8 pf = *(const bf16x8*)((char*)Ps[wid] + lrow * 128 +
                        ((j32 * 64 + g8 * 16) ^ ((lrow & 7) << 4)));
          #pragma unroll
          for (int dcb = 0; dcb < 8; ++dcb){
            int d = dcb * 16 + lrow;
            bf16x8 vf = *(const bf16x8*)((char*)VTs + d * 128 +
                          ((j32 * 64 + g8 * 16) ^ ((((d >> 3) ^ d) & 7) << 4)));
            O[dcb] = __builtin_amdgcn_mfma_f32_16x16x32_bf16(vf, pf, O[dcb], 0, 0, 0);
          }
        }
      }
    }
    float inv = 1.0f / lsum;
    #pragma unroll
    for (int dcb = 0; dcb < 8; ++dcb){
      bf16x4 w4;
      #pragma unroll
      for (int r = 0; r < 4; ++r) w4[r] = (short)f2bf(O[dcb][r] * inv);
      *(bf16x4*)(ob + ((size_t)(b * NT + tq)) * (NH * ND) + h * ND + dcb * 16 + g8 * 4) = w4;
    }
  }
}

// ---------------------------------------------------------------------------
extern "C" void kernel_launch(void* const* d_in, const int* in_sizes, int n_in,
                              void* d_out, int out_size, void* d_ws, size_t ws_size,
                              hipStream_t stream){
  const float* x  = (const float*)d_in[0];
  const float* wq = (const float*)d_in[1];
  const float* wk = (const float*)d_in[2];
  const float* wv = (const float*)d_in[3];
  const float* wo = (const float*)d_in[4];
  const float* gq = (const float*)d_in[5];
  const float* bq = (const float*)d_in[6];
  const float* gk = (const float*)d_in[7];
  const float* bk = (const float*)d_in[8];

  char* ws = (char*)d_ws;
  short* xb   = (short*)(ws);                      // 16,777,216 B
  short* wT   = (short*)(ws + 16777216);           // 33,554,432 B (q,k,v,o ^T)
  short* qkvb = (short*)(ws + 50331648);           // 50,331,648 B (q|k|v bf16 BHTD)
  short* qkn  = (short*)(ws + 100663296);          // 33,554,432 B (qn|kn)
  short* ob   = (short*)(ws + 134217728);          // 16,777,216 B
  float* ctab = (float*)(ws + 150994944);          // 524,288 B
  float* stab = (float*)(ws + 151519232);          // 524,288 B

  (void)hipFuncSetAttribute((const void*)gemm256_k,
                            hipFuncAttributeMaxDynamicSharedMemorySize, 131072);

  rope_table_k<<<dim3(2048), dim3(64), 0, stream>>>(ctab, stab);
  cast_x_k<<<dim3(8192), dim3(256), 0, stream>>>(x, xb);
  transpose_w_k<<<dim3(64, 64, 4), dim3(256), 0, stream>>>(wq, wk, wv, wo, wT);
  gemm256_k<<<dim3(384), dim3(512), 131072, stream>>>(xb, wT, qkvb);
  norm_rope_k<<<dim3(16384, 2), dim3(256), 0, stream>>>(qkvb, qkn, gq, bq, gk, bk, ctab, stab);
  attn_k<<<dim3(16, 32), dim3(256), 0, stream>>>(qkn, qkn + 8388608,
                                                 qkvb + 2 * (size_t)8388608, ob);
  gemm_bt_k<<<dim3(32, 16), dim3(256), 0, stream>>>(ob, wT + 3 * (size_t)4194304,
                                                    (float*)d_out, 2048);
}

// Round 4
// 304.208 us; speedup vs baseline: 1.1070x; 1.0629x over previous
//
#include <hip/hip_runtime.h>

// ---------------------------------------------------------------------------
// Fused MHA: B=2, T=2048, M=2048, H=16, D=128, causal, qk-centered-RMS-norm,
// half-split rotary, QK_SCALE = 1/D.
// Pipeline: cast/transposes -> QKV GEMM (256^2 8-wave bf16 MFMA, 1-barrier
// K-loop) -> norm+rope -> flash attn -> out GEMM (dbuf 128^2, fp32 out).
// ---------------------------------------------------------------------------

#define NB 2
#define NT 2048
#define NM 2048
#define NH 16
#define ND 128

typedef __attribute__((ext_vector_type(4))) float f32x4;
typedef __attribute__((ext_vector_type(8))) short bf16x8;
typedef __attribute__((ext_vector_type(4))) short bf16x4;

#define AS1 __attribute__((address_space(1)))
#define AS3 __attribute__((address_space(3)))

__device__ __forceinline__ unsigned short f2bf(float f){
  unsigned int u = __float_as_uint(f);
  u = (u + 0x7fffu + ((u >> 16) & 1u)) >> 16;   // RNE
  return (unsigned short)u;
}
__device__ __forceinline__ float bf2f(short s){
  return __uint_as_float(((unsigned int)(unsigned short)s) << 16);
}
__device__ __forceinline__ float wredsum(float v){
  #pragma unroll
  for (int m = 1; m < 64; m <<= 1) v += __shfl_xor(v, m);
  return v;
}
__device__ __forceinline__ void gload_lds16(const void* g, void* l){
  __builtin_amdgcn_global_load_lds((const AS1 void*)g, (AS3 void*)l, 16, 0, 0);
}

// ---------------- rope cos/sin table: [T][64] each --------------------------
__global__ __launch_bounds__(64) void rope_table_k(float* ctab, float* stab){
  int t = blockIdx.x, i = threadIdx.x;
  float freq = __expf(-(float)i * (9.210340371976184f / 64.0f)); // ln(10000)
  float ang = (float)t * freq;
  ctab[t * 64 + i] = cosf(ang);
  stab[t * 64 + i] = sinf(ang);
}

// ---------------- cast x fp32 -> bf16 --------------------------------------
__global__ __launch_bounds__(256) void cast_x_k(const float* __restrict__ x,
                                                short* __restrict__ xb){
  size_t gid = (size_t)blockIdx.x * 256 + threadIdx.x;
  float4 v = *(const float4*)(x + gid * 4);
  bf16x4 o;
  o[0] = (short)f2bf(v.x); o[1] = (short)f2bf(v.y);
  o[2] = (short)f2bf(v.z); o[3] = (short)f2bf(v.w);
  *(bf16x4*)(xb + gid * 4) = o;
}

// ------------- transpose weights fp32 [K][N] -> bf16 [N][K] ----------------
__global__ __launch_bounds__(256) void transpose_w_k(const float* __restrict__ wq,
                                                     const float* __restrict__ wk,
                                                     const float* __restrict__ wv,
                                                     const float* __restrict__ wo,
                                                     short* __restrict__ wT){
  __shared__ float tl[32][33];
  int z = blockIdx.z;
  const float* src = (z == 0) ? wq : (z == 1) ? wk : (z == 2) ? wv : wo;
  short* dst = wT + (size_t)z * 2048 * 2048;
  int n0 = blockIdx.x * 32, k0 = blockIdx.y * 32;
  int cx = threadIdx.x & 31, ry = threadIdx.x >> 5; // 0..7
  #pragma unroll
  for (int p = 0; p < 4; ++p)
    tl[ry + 8 * p][cx] = src[(size_t)(k0 + ry + 8 * p) * 2048 + n0 + cx];
  __syncthreads();
  #pragma unroll
  for (int p = 0; p < 4; ++p)
    dst[(size_t)(n0 + ry + 8 * p) * 2048 + k0 + cx] =
        (short)f2bf(tl[cx][ry + 8 * p]);
}

// ---------------------------------------------------------------------------
// QKV GEMM: C[4096 x 6144] = A[4096 x 2048] * B^T[6144 x 2048] (bf16)
// 256x256 tile, BK=64, 8 waves (2M x 4N), 512 threads, 128 KiB dynamic LDS.
// Minimal-sync K-loop: 1 barrier + 1 counted vmcnt per K-tile; compiler
// schedules ds_read/MFMA freely (fine-grained lgkmcnt). T1 + T2 swizzles.
// ---------------------------------------------------------------------------
#define NKT 32   // 2048 / 64
__global__ __launch_bounds__(512, 2) void gemm256_k(const short* __restrict__ A,
                                                    const short* __restrict__ Bt,
                                                    short* __restrict__ Cq){
  extern __shared__ char lds[];   // [mat(2)][buf(2)][128..256 rows][64] bf16
  const int tid = threadIdx.x;
  const int wid = tid >> 6, lane = tid & 63;
  const int lrow = lane & 15, g8 = lane >> 4;
  const int wm = wid >> 2, wn = wid & 3;
  const int Kdim = 2048;

  // XCD-aware bijective swizzle over 384 blocks (384 % 8 == 0)
  int bid = blockIdx.x;
  int s = (bid & 7) * 48 + (bid >> 3);
  const int bx = s & 15;        // 16 m-tiles
  const int by = s >> 4;        // 24 n-tiles
  const int m0 = bx * 256, n0 = by * 256;

  // staging: thread covers row = wid*8 + (lane>>3), pre-swizzled k granule
  const int r8 = lane >> 3;
  const int gcol = ((lane & 7) ^ r8) * 8;           // inverse-swizzled source
  const short* Ab = A  + (size_t)(m0 + wid * 8 + r8) * Kdim + gcol;
  const short* Bb = Bt + (size_t)(n0 + wid * 8 + r8) * Kdim + gcol;

  f32x4 acc[8][4] = {};

  auto STAGE = [&](int c, int kt){
    #pragma unroll
    for (int h = 0; h < 2; ++h)
      #pragma unroll
      for (int l = 0; l < 2; ++l){
        size_t roff = (size_t)(h * 128 + l * 64) * Kdim + kt * 64;
        char* la = lds + c * 32768 + h * 16384 + l * 8192 + wid * 1024;
        gload_lds16(Ab + roff, la);
        gload_lds16(Bb + roff, la + 65536);
      }
  };
  auto ldA = [&](int c, int mi, int kk) -> bf16x8 {
    int row = mi * 16 + lrow;
    int col = (kk * 64 + g8 * 16) ^ ((lrow & 7) << 4);
    return *(const bf16x8*)(lds + c * 32768 + wm * 16384 + row * 128 + col);
  };
  auto ldB = [&](int c, int ni, int kk) -> bf16x8 {
    int row = (wn & 1) * 64 + ni * 16 + lrow;
    int col = (kk * 64 + g8 * 16) ^ ((lrow & 7) << 4);
    return *(const bf16x8*)(lds + 65536 + c * 32768 + (wn >> 1) * 16384 + row * 128 + col);
  };

  STAGE(0, 0);   // prologue

  for (int kt = 0; kt < NKT; ++kt){
    const int c = kt & 1;
    // tile kt's loads were issued one full tile ago (except kt=0) -> no stall
    asm volatile("s_waitcnt vmcnt(0)" ::: "memory");
    __builtin_amdgcn_s_barrier();
    if (kt + 1 < NKT) STAGE(c ^ 1, kt + 1);

    #pragma unroll
    for (int kk = 0; kk < 2; ++kk){
      bf16x8 bfr[4];
      #pragma unroll
      for (int ni = 0; ni < 4; ++ni) bfr[ni] = ldB(c, ni, kk);
      #pragma unroll
      for (int mh = 0; mh < 2; ++mh){
        bf16x8 afr[4];
        #pragma unroll
        for (int mi = 0; mi < 4; ++mi) afr[mi] = ldA(c, mh * 4 + mi, kk);
        #pragma unroll
        for (int mi = 0; mi < 4; ++mi)
          #pragma unroll
          for (int ni = 0; ni < 4; ++ni)
            acc[mh * 4 + mi][ni] = __builtin_amdgcn_mfma_f32_16x16x32_bf16(
                afr[mi], bfr[ni], acc[mh * 4 + mi][ni], 0, 0, 0);
      }
    }
  }

  // ---- scatter epilogue: bf16 into q|k|v [B,H,T,D] ----
  #pragma unroll
  for (int mi = 0; mi < 8; ++mi){
    int rowb = m0 + wm * 128 + mi * 16 + g8 * 4;
    #pragma unroll
    for (int ni = 0; ni < 4; ++ni){
      int col = n0 + wn * 64 + ni * 16 + lrow;
      int tsel = col >> 11;
      int hd = col & 2047;
      int hh = hd >> 7, d = hd & 127;
      short* dst = Cq + (size_t)tsel * (NB * NH * NT * ND);
      f32x4 a = acc[mi][ni];
      #pragma unroll
      for (int r = 0; r < 4; ++r){
        int bt = rowb + r;
        int b = bt >> 11, t = bt & 2047;
        dst[(((size_t)(b * NH + hh)) * NT + t) * ND + d] = (short)f2bf(a[r]);
      }
    }
  }
}

// ---------------- out-proj GEMM (128^2, double-buffered, 1-barrier) --------
// C[4096 x 2048] = A[4096 x K] * B^T[2048 x K], fp32 row-major out
__global__ __launch_bounds__(256) void gemm_bt_k(const short* __restrict__ A,
                                                 const short* __restrict__ Bt,
                                                 float* __restrict__ Cout,
                                                 int Kdim){
  __shared__ short As[2][128 * 32];
  __shared__ short Bs[2][128 * 32];
  const int tid = threadIdx.x;
  const int wid = tid >> 6, lane = tid & 63;
  const int lrow = lane & 15, g8 = lane >> 4;
  const int wm = wid >> 1, wn = wid & 1;
  const int m0 = blockIdx.x * 128, n0 = blockIdx.y * 128;
  f32x4 acc[4][4] = {};
  const int srow = lane >> 2;
  const int skcol = (lane & 3) * 8;

  auto STAGE = [&](int c, int kt){
    #pragma unroll
    for (int i = 0; i < 2; ++i){
      int inst = wid * 2 + i;
      int r = inst * 16 + srow;
      const short* sa = A  + (size_t)(m0 + r) * Kdim + kt + skcol;
      const short* sb = Bt + (size_t)(n0 + r) * Kdim + kt + skcol;
      gload_lds16(sa, (char*)As[c] + inst * 1024);
      gload_lds16(sb, (char*)Bs[c] + inst * 1024);
    }
  };

  STAGE(0, 0);
  const int nkt = Kdim >> 5;
  for (int it = 0; it < nkt; ++it){
    const int c = it & 1;
    asm volatile("s_waitcnt vmcnt(0)" ::: "memory");
    __builtin_amdgcn_s_barrier();
    if (it + 1 < nkt) STAGE(c ^ 1, (it + 1) << 5);

    bf16x8 af[4], bfv[4];
    #pragma unroll
    for (int mi = 0; mi < 4; ++mi)
      af[mi] = *(const bf16x8*)&As[c][(wm * 64 + mi * 16 + lrow) * 32 + g8 * 8];
    #pragma unroll
    for (int ni = 0; ni < 4; ++ni)
      bfv[ni] = *(const bf16x8*)&Bs[c][(wn * 64 + ni * 16 + lrow) * 32 + g8 * 8];
    #pragma unroll
    for (int mi = 0; mi < 4; ++mi)
      #pragma unroll
      for (int ni = 0; ni < 4; ++ni)
        acc[mi][ni] = __builtin_amdgcn_mfma_f32_16x16x32_bf16(
            af[mi], bfv[ni], acc[mi][ni], 0, 0, 0);
  }

  #pragma unroll
  for (int mi = 0; mi < 4; ++mi){
    int rowb = m0 + wm * 64 + mi * 16 + g8 * 4;
    #pragma unroll
    for (int ni = 0; ni < 4; ++ni){
      int col = n0 + wn * 64 + ni * 16 + lrow;
      f32x4 a = acc[mi][ni];
      #pragma unroll
      for (int r = 0; r < 4; ++r)
        Cout[(size_t)(rowb + r) * 2048 + col] = a[r];
    }
  }
}

// -------------- centered RMS norm + rotary (q and k) -----------------------
__global__ __launch_bounds__(256) void norm_rope_k(const short* __restrict__ qkv,
                                                   short* __restrict__ outp,
                                                   const float* __restrict__ gq,
                                                   const float* __restrict__ bq,
                                                   const float* __restrict__ gk,
                                                   const float* __restrict__ bk,
                                                   const float* __restrict__ ctab,
                                                   const float* __restrict__ stab){
  int which = blockIdx.y;
  const short* src = qkv + (size_t)which * (NB * NH * NT * ND);
  short* dst = outp + (size_t)which * (NB * NH * NT * ND);
  const float* g = which ? gk : gq;
  const float* bb = which ? bk : bq;
  int wid = threadIdx.x >> 6, lane = threadIdx.x & 63;
  size_t row = (size_t)blockIdx.x * 4 + wid;  // over B*H*T
  int h = (int)((row >> 11) & 15);
  int t = (int)(row & 2047);
  const short* rp = src + row * ND;
  float v0 = bf2f(rp[lane]), v1 = bf2f(rp[lane + 64]);
  float mean = wredsum(v0 + v1) * (1.0f / 128.0f);
  float c0 = v0 - mean, c1 = v1 - mean;
  float ms = wredsum(c0 * c0 + c1 * c1) * (1.0f / 128.0f);
  float rstd = rsqrtf(ms + 1e-6f);
  float n0 = c0 * rstd * (1.0f + g[h * ND + lane]) + bb[h * ND + lane];
  float n1 = c1 * rstd * (1.0f + g[h * ND + lane + 64]) + bb[h * ND + lane + 64];
  float co = ctab[t * 64 + lane], si = stab[t * 64 + lane];
  short* wp = dst + row * ND;
  wp[lane]      = (short)f2bf(n0 * co - n1 * si);
  wp[lane + 64] = (short)f2bf(n0 * si + n1 * co);
}

// ---------------- flash attention, causal ----------------------------------
__global__ __launch_bounds__(256) void attn_k(const short* __restrict__ qn,
                                              const short* __restrict__ kn,
                                              const short* __restrict__ vsrc,
                                              short* __restrict__ ob){
  __shared__ short Ks[64 * 128];
  __shared__ short VTs[128 * 64];
  __shared__ short Ps[4][16 * 64];
  const int tid = threadIdx.x;
  const int wid = tid >> 6, lane = tid & 63;
  const int lrow = lane & 15, g8 = lane >> 4;
  const int bh = blockIdx.y;
  const int b = bh >> 4, h = bh & 15;
  const size_t base = (size_t)bh * NT * ND;

  for (int pass = 0; pass < 2; ++pass){
    const int qt = pass ? (31 - (int)blockIdx.x) : (int)blockIdx.x;
    const int t0 = qt * 64;
    const int tq = t0 + wid * 16 + lrow;
    bf16x8 qf[4];
    #pragma unroll
    for (int dc = 0; dc < 4; ++dc)
      qf[dc] = *(const bf16x8*)(qn + base + (size_t)tq * ND + dc * 32 + g8 * 8);
    f32x4 O[8] = {};
    float m = -3e38f, lsum = 0.0f;
    const int ntiles = qt + 1;

    for (int jb = 0; jb < ntiles; ++jb){
      __syncthreads();
      #pragma unroll
      for (int p = 0; p < 4; ++p){
        int r = (tid >> 4) + p * 16;
        int c = tid & 15;
        bf16x8 kv = *(const bf16x8*)(kn + base + (size_t)(jb * 64 + r) * ND + c * 8);
        *(bf16x8*)((char*)Ks + r * 256 + ((c * 16) ^ ((r & 7) << 4))) = kv;
      }
      #pragma unroll
      for (int p = 0; p < 4; ++p){
        int jr = (tid >> 4) + p * 16;
        int d0 = (tid & 15) * 8;
        bf16x8 vv = *(const bf16x8*)(vsrc + base + (size_t)(jb * 64 + jr) * ND + d0);
        #pragma unroll
        for (int i = 0; i < 8; ++i){
          int d = d0 + i;
          *(short*)((char*)VTs + d * 128 +
                    ((jr * 2) ^ ((((d >> 3) ^ d) & 7) << 4))) = vv[i];
        }
      }
      __syncthreads();

      if (jb * 64 <= t0 + wid * 16 + 15){
        f32x4 st[4] = {};
        #pragma unroll
        for (int dc = 0; dc < 4; ++dc)
          #pragma unroll
          for (int js = 0; js < 4; ++js){
            int jl = js * 16 + lrow;
            bf16x8 kf = *(const bf16x8*)((char*)Ks + jl * 256 +
                          ((dc * 64 + g8 * 16) ^ ((jl & 7) << 4)));
            st[js] = __builtin_amdgcn_mfma_f32_16x16x32_bf16(kf, qf[dc], st[js], 0, 0, 0);
          }
        float mx = -3e38f;
        #pragma unroll
        for (int js = 0; js < 4; ++js)
          #pragma unroll
          for (int r = 0; r < 4; ++r){
            float s = st[js][r] * (1.0f / 128.0f);
            int j = jb * 64 + js * 16 + g8 * 4 + r;
            if (j > tq) s = -3e38f;
            st[js][r] = s;
            mx = fmaxf(mx, s);
          }
        mx = fmaxf(mx, __shfl_xor(mx, 16));
        mx = fmaxf(mx, __shfl_xor(mx, 32));
        float mnew = fmaxf(m, mx);
        float fac = __expf(m - mnew);
        m = mnew;
        lsum *= fac;
        #pragma unroll
        for (int dcb = 0; dcb < 8; ++dcb) O[dcb] *= fac;
        float ps = 0.0f;
        #pragma unroll
        for (int js = 0; js < 4; ++js)
          #pragma unroll
          for (int r = 0; r < 4; ++r){
            float p = __expf(st[js][r] - mnew);
            ps += p;
            int jl = js * 16 + g8 * 4 + r;
            *(short*)((char*)Ps[wid] + lrow * 128 +
                      ((jl * 2) ^ ((lrow & 7) << 4))) = (short)f2bf(p);
          }
        ps += __shfl_xor(ps, 16);
        ps += __shfl_xor(ps, 32);
        lsum += ps;
        asm volatile("s_waitcnt lgkmcnt(0)" ::: "memory");
        #pragma unroll
        for (int j32 = 0; j32 < 2; ++j32){
          bf16x8 pf = *(const bf16x8*)((char*)Ps[wid] + lrow * 128 +
                        ((j32 * 64 + g8 * 16) ^ ((lrow & 7) << 4)));
          #pragma unroll
          for (int dcb = 0; dcb < 8; ++dcb){
            int d = dcb * 16 + lrow;
            bf16x8 vf = *(const bf16x8*)((char*)VTs + d * 128 +
                          ((j32 * 64 + g8 * 16) ^ ((((d >> 3) ^ d) & 7) << 4)));
            O[dcb] = __builtin_amdgcn_mfma_f32_16x16x32_bf16(vf, pf, O[dcb], 0, 0, 0);
          }
        }
      }
    }
    float inv = 1.0f / lsum;
    #pragma unroll
    for (int dcb = 0; dcb < 8; ++dcb){
      bf16x4 w4;
      #pragma unroll
      for (int r = 0; r < 4; ++r) w4[r] = (short)f2bf(O[dcb][r] * inv);
      *(bf16x4*)(ob + ((size_t)(b * NT + tq)) * (NH * ND) + h * ND + dcb * 16 + g8 * 4) = w4;
    }
  }
}

// ---------------------------------------------------------------------------
extern "C" void kernel_launch(void* const* d_in, const int* in_sizes, int n_in,
                              void* d_out, int out_size, void* d_ws, size_t ws_size,
                              hipStream_t stream){
  const float* x  = (const float*)d_in[0];
  const float* wq = (const float*)d_in[1];
  const float* wk = (const float*)d_in[2];
  const float* wv = (const float*)d_in[3];
  const float* wo = (const float*)d_in[4];
  const float* gq = (const float*)d_in[5];
  const float* bq = (const float*)d_in[6];
  const float* gk = (const float*)d_in[7];
  const float* bk = (const float*)d_in[8];

  char* ws = (char*)d_ws;
  short* xb   = (short*)(ws);                      // 16,777,216 B
  short* wT   = (short*)(ws + 16777216);           // 33,554,432 B (q,k,v,o ^T)
  short* qkvb = (short*)(ws + 50331648);           // 50,331,648 B (q|k|v bf16 BHTD)
  short* qkn  = (short*)(ws + 100663296);          // 33,554,432 B (qn|kn)
  short* ob   = (short*)(ws + 134217728);          // 16,777,216 B
  float* ctab = (float*)(ws + 150994944);          // 524,288 B
  float* stab = (float*)(ws + 151519232);          // 524,288 B

  (void)hipFuncSetAttribute((const void*)gemm256_k,
                            hipFuncAttributeMaxDynamicSharedMemorySize, 131072);

  rope_table_k<<<dim3(2048), dim3(64), 0, stream>>>(ctab, stab);
  cast_x_k<<<dim3(8192), dim3(256), 0, stream>>>(x, xb);
  transpose_w_k<<<dim3(64, 64, 4), dim3(256), 0, stream>>>(wq, wk, wv, wo, wT);
  gemm256_k<<<dim3(384), dim3(512), 131072, stream>>>(xb, wT, qkvb);
  norm_rope_k<<<dim3(16384, 2), dim3(256), 0, stream>>>(qkvb, qkn, gq, bq, gk, bk, ctab, stab);
  attn_k<<<dim3(16, 32), dim3(256), 0, stream>>>(qkn, qkn + 8388608,
                                                 qkvb + 2 * (size_t)8388608, ob);
  gemm_bt_k<<<dim3(32, 16), dim3(256), 0, stream>>>(ob, wT + 3 * (size_t)4194304,
                                                    (float*)d_out, 2048);
}